// Round 11
// baseline (109.482 us; speedup 1.0000x reference)
//
#include <hip/hip_runtime.h>

// Network24 — ROUND 11: DECISIVE MEASUREMENT (4-pass self-replication).
// R3-R10: every source-level lever (coalescing, NT, persistence, dbuf, ILP,
// wave count, VALU count, trans ops) is NEUTRAL; math kernels ~39-47 us,
// same-shape mathless copy >=6.2 TB/s. Remaining suspects: (a) compute-clock
// ramp after the harness's ~68us memory-only reset phase (fixed ~30-40us tax
// on any VALU-bearing kernel), vs (b) intrinsic per-pass cost.
// This kernel runs the FULL load->math->store pipeline 4x (idempotent stores,
// memory clobber defeats CSE). T1~=39 known; T4 measured via rocprof (kernel
// will rank #1): T4 = W + 4S, T1 = W + S.
//   (a) -> T4 ~ 60-75, VALUBusy>50%, FETCH~33MB.  (b) -> T4 ~ 150-160.

typedef float vfloat4 __attribute__((ext_vector_type(4)));
typedef float vfloat2 __attribute__((ext_vector_type(2)));

__device__ __forceinline__ float sigmoid_exact(float z) {
    return 1.0f / (1.0f + expf(-z));
}
__device__ __forceinline__ float pw(float x, float p) {
    return (p == 1.0f) ? x : __powf(x, p);
}

__global__ __launch_bounds__(256) void net24_kernel(
    const float* __restrict__ x,        // (n, 2) row-major
    float* __restrict__ out,            // (n,)
    const float* __restrict__ fc1_tw,   // (2,2,3) -> [j,k,0] = j*6+k*3
    const float* __restrict__ fc1_power,// (2,2)
    const float* __restrict__ fc1_bias, // (2,)
    const float* __restrict__ m4_tw,    // (4,3) -> [i,0] = i*3
    const float* __restrict__ m4_power, // (4,)
    const float* __restrict__ m4_bias3, // (1,)
    int n,
    int npass)                          // 4: diagnostic replication factor
{
    const float tw00 = fc1_tw[0], tw01 = fc1_tw[3], tw10 = fc1_tw[6], tw11 = fc1_tw[9];
    const float p00 = fc1_power[0], p01 = fc1_power[1], p10 = fc1_power[2], p11 = fc1_power[3];
    const float b0 = fc1_bias[0], b1 = fc1_bias[1];
    const float m0 = m4_tw[0], m1 = m4_tw[3], m2 = m4_tw[6], m3 = m4_tw[9];
    const float q0 = m4_power[0], q1 = m4_power[1], q2 = m4_power[2], q3 = m4_power[3];
    const float bias3 = m4_bias3[0];

    const bool all_pow1 = (p00 == 1.0f) & (p01 == 1.0f) & (p10 == 1.0f) & (p11 == 1.0f) &
                          (q0 == 1.0f) & (q1 == 1.0f) & (q2 == 1.0f) & (q3 == 1.0f);

    // Pre-negated constants: each sigmoid consumes -z directly.
    const float ntw00 = -tw00, ntw01 = -tw01, nb0 = -b0;
    const float ntw10 = -tw10, ntw11 = -tw11, nb1 = -b1;
    const float nm0 = -m0, nm1 = -m1, nM = -(m2 * m3), nbias3 = -bias3;

    auto eval_fast = [&](float x0, float x1) -> float {
        float zn0 = fmaf(ntw00, x0, fmaf(ntw01, x1, nb0));
        float zn1 = fmaf(ntw10, x0, fmaf(ntw11, x1, nb1));
        float h0 = __builtin_amdgcn_rcpf(1.0f + __expf(zn0));
        float h1 = __builtin_amdgcn_rcpf(1.0f + __expf(zn1));
        float sn = fmaf(nM * h0, h1, fmaf(nm0, h0, fmaf(nm1, h1, nbias3)));
        return __builtin_amdgcn_rcpf(1.0f + __expf(sn));
    };
    auto eval_gen = [&](float x0, float x1) -> float {
        float h0 = sigmoid_exact(fmaf(tw00, pw(x0, p00), fmaf(tw01, pw(x1, p01), b0)));
        float h1 = sigmoid_exact(fmaf(tw10, pw(x0, p10), fmaf(tw11, pw(x1, p11), b1)));
        float s  = fmaf(m0, pw(h0, q0), fmaf(m1, pw(h1, q1), bias3));
        s = fmaf(m2 * pw(h0, q2), m3 * pw(h1, q3), s);
        return sigmoid_exact(s);
    };

    const int gid  = blockIdx.x * blockDim.x + threadIdx.x;
    const int wave = gid >> 6;
    const int lane = gid & 63;
    const long long rowbase = (long long)wave * 256;   // 256-row wave-tile
    if (rowbase >= n) return;

    if (all_pow1 && rowbase + 256 <= n) {
        for (int pass = 0; pass < npass; ++pass) {
            // Full pipeline each pass: coalesced loads, math, coalesced stores.
            const vfloat4* xv = (const vfloat4*)(x + rowbase * 2);
            vfloat4 a = xv[lane];
            vfloat4 b = xv[64 + lane];
            vfloat2 ra, rb;
            ra.x = eval_fast(a.x, a.y);
            ra.y = eval_fast(a.z, a.w);
            rb.x = eval_fast(b.x, b.y);
            rb.y = eval_fast(b.z, b.w);
            *(vfloat2*)(out + rowbase + 2 * lane)       = ra;
            *(vfloat2*)(out + rowbase + 128 + 2 * lane) = rb;
            // Defeat CSE/store-merging across passes; stores are idempotent.
            asm volatile("" ::: "memory");
        }
    } else {
        for (long long r = rowbase + lane; r < rowbase + 256 && r < n; r += 64) {
            out[r] = eval_gen(x[r * 2], x[r * 2 + 1]);
        }
    }
}

extern "C" void kernel_launch(void* const* d_in, const int* in_sizes, int n_in,
                              void* d_out, int out_size, void* d_ws, size_t ws_size,
                              hipStream_t stream) {
    const float* x         = (const float*)d_in[0];
    const float* fc1_tw    = (const float*)d_in[1];
    const float* fc1_power = (const float*)d_in[2];
    const float* fc1_bias  = (const float*)d_in[3];
    const float* m4_tw     = (const float*)d_in[4];
    const float* m4_power  = (const float*)d_in[5];
    const float* m4_bias3  = (const float*)d_in[6];
    float* out = (float*)d_out;

    const int n = out_size;                               // 8388608 rows
    const long long waves = ((long long)n + 255) / 256;   // 32768 wave-tiles
    const long long threads = waves * 64;
    const long long grid = (threads + 255) / 256;         // 8192 blocks

    net24_kernel<<<(int)grid, 256, 0, stream>>>(x, out, fc1_tw, fc1_power, fc1_bias,
                                                m4_tw, m4_power, m4_bias3, n,
                                                /*npass=*/4);
}